// Round 5
// baseline (221.814 us; speedup 1.0000x reference)
//
#include <hip/hip_runtime.h>

// FusedMultiPool: out[b,s,h,w] = max_{k<8} x[b, idx[s,k], h, w]
// B=32, C=256, H=64, W=64, S=128, K=8. fp32.
//
// LDS-staging, fine-grained (R5): chunk = 16 floats (4 f4) per channel.
//   block = (b, chunk); LDS = 256 ch x 4 f4 x 16B = 16 KiB -> 10 blocks/CU
//   (vs 5 at 32 KiB), 8192 blocks = 32 generations/CU for deep pipelining of
//   the stage->barrier->gather cycle.
// Phase 1: global_load_lds(16B) stages all 256 channels' chunk. Thread t,
//   round r -> lds slot t+256r == c*4+j with c=(t>>2)+64r, j=t&3: 4-lane
//   groups fetch one 64B cache line per channel, 16 lines/instruction --
//   zero DRAM waste, lane-contiguous LDS dest (global_load_lds requirement).
// Phase 2: thread t computes s = (t>>2) and (t>>2)+64, f4 lane j: max of 8
//   LDS gathers lds[idx[s][k]*4 + j]; NT store (out is write-once).
// Global traffic is exactly compulsory: 128 MiB x + 64 MiB out + idx (~L2).

constexpr int Bb = 32, Cc = 256, Hh = 64, Ww = 64, Ss = 128, Kk = 8;
constexpr int CF4     = 4;                     // 4 float4 = 16 floats/channel
constexpr int NCHUNK  = (Hh * Ww / 4) / CF4;   // 256 chunks per plane
constexpr int PLANEF4 = Hh * Ww / 4;           // 1024 f4 per plane

typedef float f4 __attribute__((ext_vector_type(4)));
typedef int   i4 __attribute__((ext_vector_type(4)));

__device__ __forceinline__ f4 fmax4(f4 a, f4 b) {
    f4 r;
    r.x = fmaxf(a.x, b.x);
    r.y = fmaxf(a.y, b.y);
    r.z = fmaxf(a.z, b.z);
    r.w = fmaxf(a.w, b.w);
    return r;
}

__global__ __launch_bounds__(256) void fmp_kernel(
    const f4* __restrict__ x4,
    const int* __restrict__ idx,
    f4*       __restrict__ out4)
{
    __shared__ f4 lds[Cc * CF4];               // 1024 f4 = 16 KiB, [c][j]

    const int t     = threadIdx.x;
    const int b     = blockIdx.x >> 8;         // 256 chunks per b (uniform)
    const int chunk = blockIdx.x & (NCHUNK - 1);
    const int j     = t & 3;
    const int q     = t >> 2;                  // 0..63 (channel base / s base)

    // ---- Phase 1: stage all 256 channels' 64B chunk into LDS ----
    const f4* gbase = x4 + (size_t)b * (Cc * PLANEF4) + chunk * CF4 + j;
    #pragma unroll
    for (int r = 0; r < 4; ++r) {
        const f4* g = gbase + (size_t)(q + 64 * r) * PLANEF4;
        __builtin_amdgcn_global_load_lds(
            (const __attribute__((address_space(1))) void*)g,
            (__attribute__((address_space(3))) void*)&lds[t + 256 * r],
            16, 0, 0);
    }

    // ---- idx rows for this thread's 2 s values (L2-hot) ----
    i4 ia[2], ib[2];
    #pragma unroll
    for (int r = 0; r < 2; ++r) {
        const i4* ir = (const i4*)(idx + (q + 64 * r) * Kk);
        ia[r] = ir[0];
        ib[r] = ir[1];
    }

    __syncthreads();

    // ---- Phase 2: gather-max from LDS, NT store ----
    const size_t obase = (size_t)b * (Ss * PLANEF4) + chunk * CF4 + j;
    #pragma unroll
    for (int r = 0; r < 2; ++r) {
        const int s = q + 64 * r;
        f4 m =       lds[ia[r].x * CF4 + j];
        m = fmax4(m, lds[ia[r].y * CF4 + j]);
        m = fmax4(m, lds[ia[r].z * CF4 + j]);
        m = fmax4(m, lds[ia[r].w * CF4 + j]);
        m = fmax4(m, lds[ib[r].x * CF4 + j]);
        m = fmax4(m, lds[ib[r].y * CF4 + j]);
        m = fmax4(m, lds[ib[r].z * CF4 + j]);
        m = fmax4(m, lds[ib[r].w * CF4 + j]);
        __builtin_nontemporal_store(m, &out4[obase + (size_t)s * PLANEF4]);
    }
}

extern "C" void kernel_launch(void* const* d_in, const int* in_sizes, int n_in,
                              void* d_out, int out_size, void* d_ws, size_t ws_size,
                              hipStream_t stream) {
    const f4*  x4  = (const f4*)d_in[0];
    const int* idx = (const int*)d_in[1];
    f4*        o4  = (f4*)d_out;

    const int blocks = Bb * NCHUNK;            // 32 * 256 = 8192
    fmp_kernel<<<blocks, 256, 0, stream>>>(x4, idx, o4);
}

// Round 6
// 209.817 us; speedup vs baseline: 1.0572x; 1.0572x over previous
//
#include <hip/hip_runtime.h>

// FusedMultiPool: out[b,s,h,w] = max_{k<8} x[b, idx[s,k], h, w]
// B=32, C=256, H=64, W=64, S=128, K=8. fp32.
//
// R6: direct-gather (R0 structure) + XCD-pinned L2 blocking.
//   task = (b, quarter) = 256 channels x 4KiB quarter-region = 1 MiB of x.
//   One block per (task, s): 256 threads, one f4 output each, 8 SGPR-offset
//   coalesced gathers (4 KiB per load instruction).
//   bid = inner*8 + xcd pins task sequences to XCDs (round-robin dispatch
//   heuristic): XCD x runs tasks {x, x+8, ...}, 128 s-blocks per task back to
//   back -> the 1 MiB region is read from HBM once and re-served 3x from the
//   XCD's 4 MiB L2 (transient working set ~2-3 MiB incl. task overlap, 4x
//   margin vs R3's exact-capacity failure). NT stores bypass L2.
// HBM: compulsory 128 MiB x + 64 MiB out ~ 31 us; L2 reuse 384 MiB ~ 11 us
// (overlapped). Fallback if %8 mapping fails: L3-served, ~R0 performance.

constexpr int Bb = 32, Cc = 256, Hh = 64, Ww = 64, Ss = 128, Kk = 8;
constexpr int PLANEF4 = Hh * Ww / 4;   // 1024 f4 per channel plane
constexpr int QF4     = PLANEF4 / 4;   // 256 f4 per quarter-region

typedef float f4 __attribute__((ext_vector_type(4)));

__device__ __forceinline__ f4 fmax4(f4 a, f4 b) {
    f4 r;
    r.x = fmaxf(a.x, b.x);
    r.y = fmaxf(a.y, b.y);
    r.z = fmaxf(a.z, b.z);
    r.w = fmaxf(a.w, b.w);
    return r;
}

__global__ __launch_bounds__(256) void fmp_kernel(
    const f4* __restrict__ x4,
    const int* __restrict__ idx,
    f4*       __restrict__ out4)
{
    const unsigned bid   = blockIdx.x;
    const unsigned xcd   = bid & 7u;          // round-robin XCD (heuristic)
    const unsigned inner = bid >> 3;          // per-XCD sequence 0..2047
    const unsigned tl    = inner >> 7;        // task_local 0..15
    const unsigned s     = inner & 127u;      // block-uniform
    const unsigned tg    = tl * 8u + xcd;     // task_global 0..127
    const unsigned b     = tg >> 2;           // block-uniform
    const unsigned quarter = tg & 3u;

    const int t    = threadIdx.x;
    const unsigned qoff = quarter * QF4 + t;  // f4 offset within plane

    const int* __restrict__ ip = idx + s * Kk;           // uniform -> s_load
    const f4* __restrict__ xb  = x4 + (size_t)b * (Cc * PLANEF4) + qoff;

    f4 m =       xb[(size_t)ip[0] * PLANEF4];
    #pragma unroll
    for (int k = 1; k < Kk; ++k)
        m = fmax4(m, xb[(size_t)ip[k] * PLANEF4]);

    const size_t o = ((size_t)b * Ss + s) * PLANEF4 + qoff;
    __builtin_nontemporal_store(m, (f4*)&out4[o]);
}

extern "C" void kernel_launch(void* const* d_in, const int* in_sizes, int n_in,
                              void* d_out, int out_size, void* d_ws, size_t ws_size,
                              hipStream_t stream) {
    const f4*  x4  = (const f4*)d_in[0];
    const int* idx = (const int*)d_in[1];
    f4*        o4  = (f4*)d_out;

    const int blocks = Bb * Ss * 4;            // 128 tasks * 128 s = 16384
    fmp_kernel<<<blocks, 256, 0, stream>>>(x4, idx, o4);
}